// Round 14
// baseline (208.051 us; speedup 1.0000x reference)
//
#include <hip/hip_runtime.h>

// Problem constants
#define NB      20000      // nodes per batch
#define BATCH   4
#define KNN     16
#define DD      128        // embedding dim
#define BM      32         // nodes per block (32 -> 2504 blocks, ~9.8/CU)
#define MW      136        // bf16 LDS row stride, padded from 128
#define NSLOT   313        // blocks per XCD half-batch: 313*32 = 10016 rows
#define GRID_MAIN (8*NSLOT)

#if defined(__has_builtin)
#if __has_builtin(__builtin_amdgcn_cvt_pk_f32_fp8)
#define FP8_DEC_BUILTIN 1
#endif
#endif

typedef __attribute__((ext_vector_type(8))) short          bf16x8;
typedef __attribute__((ext_vector_type(4))) float          f32x4;
typedef __attribute__((ext_vector_type(2))) float          f32x2;
typedef __attribute__((ext_vector_type(4))) int            i32x4;
typedef __attribute__((ext_vector_type(2))) int            i32x2;
typedef __attribute__((ext_vector_type(4))) unsigned short u16x4;
typedef __attribute__((ext_vector_type(8))) unsigned short u16x8;

__device__ __forceinline__ unsigned short f2bf(float f) {
    unsigned int u = __float_as_uint(f);
    u += 0x7fffu + ((u >> 16) & 1u);           // round-to-nearest-even
    return (unsigned short)(u >> 16);
}
__device__ __forceinline__ float bf2f(unsigned short u) {
    return __uint_as_float((unsigned int)u << 16);
}

__device__ __forceinline__ unsigned int f32_to_e4m3(float x) {
    unsigned int u   = __float_as_uint(x);
    unsigned int sgn = (u >> 24) & 0x80u;
    float ax = fabsf(x);
    unsigned int em;
    if (ax < 0.015625f) {                       // denormal: m * 2^-9
        em = (unsigned int)rintf(ax * 512.0f);
    } else {
        unsigned int mag = __float_as_uint(fminf(ax, 448.0f));
        em = ((mag + 0x7FFFFu + ((mag >> 20) & 1u)) >> 20) - 0x3C0u;
    }
    return sgn | em;
}

__device__ __forceinline__ void acc4_fp8(unsigned int w, float* s) {
#if defined(FP8_DEC_BUILTIN)
    f32x2 lo = __builtin_amdgcn_cvt_pk_f32_fp8((int)w, false);
    f32x2 hi = __builtin_amdgcn_cvt_pk_f32_fp8((int)w, true);
    s[0] += lo[0]; s[1] += lo[1]; s[2] += hi[0]; s[3] += hi[1];
#else
    #pragma unroll
    for (int j = 0; j < 4; ++j) {
        unsigned int b  = (w >> (8 * j)) & 0xFFu;
        unsigned int em = b & 0x7Fu;
        float f  = __uint_as_float((em << 20) + 0x3C000000u);
        float fd = (float)em * 0.001953125f;
        f = (em < 8u) ? fd : f;
        f = __uint_as_float(__float_as_uint(f) | ((b & 0x80u) << 24));
        s[j] += f;
    }
#endif
}

__global__ __launch_bounds__(256) void nr_prep_w(
    const float* __restrict__ W1, const float* __restrict__ W2,
    unsigned short* __restrict__ W1aT, unsigned short* __restrict__ W1bT,
    unsigned short* __restrict__ W2T)
{
    int tid = blockIdx.x * 256 + threadIdx.x;   // < 49152
    int col = (tid & 16383) / DD;
    int k   = (tid & 16383) % DD;
    if (tid < 16384) {
        W1aT[tid] = f2bf(W1[k * DD + col] + W1[(256 + k) * DD + col]);
    } else if (tid < 32768) {
        W1bT[tid - 16384] = f2bf(W1[(128 + k) * DD + col] - W1[(256 + k) * DD + col]);
    } else {
        W2T[tid - 32768] = f2bf(W2[k * DD + col]);
    }
}

__global__ __launch_bounds__(256) void nr_prep_q(
    const float* __restrict__ src, unsigned char* __restrict__ dstq)
{
    long long i = ((long long)blockIdx.x * 256 + threadIdx.x) * 8;
    const float4* p = (const float4*)(src + i);
    float4 a = p[0], b = p[1];
    unsigned int w0 = f32_to_e4m3(a.x) | (f32_to_e4m3(a.y) << 8) |
                      (f32_to_e4m3(a.z) << 16) | (f32_to_e4m3(a.w) << 24);
    unsigned int w1 = f32_to_e4m3(b.x) | (f32_to_e4m3(b.y) << 8) |
                      (f32_to_e4m3(b.z) << 16) | (f32_to_e4m3(b.w) << 24);
    i32x2 q; q[0] = (int)w0; q[1] = (int)w1;
    *(i32x2*)(dstq + i) = q;
}

// Ablation variants (fp8 tier). V=0 full (R11-identical, writes out LAST).
// V=1 gather-only (knn + x-stage + fp8 gather -> checksum to out).
// V=2 no-gather (x-stage, mean:=x, GEMMs+GELU+epilogue -> out).
// V=3 stream-only (x-stage -> store to out).
template<int V>
__global__ __launch_bounds__(256, 4) void nr_abl(
    const float* __restrict__ emb, const unsigned char* __restrict__ embq,
    const int* __restrict__ knn,
    const unsigned short* __restrict__ W1aT, const unsigned short* __restrict__ W1bT,
    const unsigned short* __restrict__ W2T,
    const float* __restrict__ b1, const float* __restrict__ b2,
    float* __restrict__ out)
{
    extern __shared__ unsigned short lds[];     // [32][MW] bf16: mean -> h -> upd
    unsigned short* ldsx = lds + BM * MW;       // [32][MW] bf16: x

    const int t     = threadIdx.x;
    const int xcd   = blockIdx.x & 7;
    const int slot  = blockIdx.x >> 3;
    const int batch = xcd >> 1;
    const int bib   = (xcd & 1) * NSLOT + slot;
    const int m_base = batch * NB + bib * BM;
    const int mend   = batch * NB + NB;

    // -------- Phase 1
    {
        const int node_local = t >> 3;          // 0..31
        const int dpart      = t & 7;           // 16 dims each
        int m = m_base + node_local;
        if (m >= mend) m = mend - 1;

        // stage x: coalesced f32 -> bf16 -> ldsx
        {
            const f32x4* xp = (const f32x4*)(emb + (long long)m * DD + dpart * 16);
            unsigned short* xrow = ldsx + node_local * MW + dpart * 16;
            unsigned short* mrow = lds  + node_local * MW + dpart * 16;
            #pragma unroll
            for (int j = 0; j < 4; ++j) {
                f32x4 v = __builtin_nontemporal_load(xp + j);
                u16x4 o;
                o[0]=f2bf(v[0]); o[1]=f2bf(v[1]); o[2]=f2bf(v[2]); o[3]=f2bf(v[3]);
                *(u16x4*)(xrow + j*4) = o;
                if constexpr (V == 2) *(u16x4*)(mrow + j*4) = o;   // mean := x
            }
        }

        if constexpr (V == 0 || V == 1) {
            int idx[KNN];
            const i32x4* kp4 = (const i32x4*)(knn + (long long)m * KNN);
            #pragma unroll
            for (int q = 0; q < 4; ++q) {
                i32x4 v = __builtin_nontemporal_load(kp4 + q);
                idx[4*q+0] = v[0]; idx[4*q+1] = v[1];
                idx[4*q+2] = v[2]; idx[4*q+3] = v[3];
            }

            float sm[16];
            #pragma unroll
            for (int e = 0; e < 16; ++e) sm[e] = 0.f;

            const unsigned char* qbase =
                embq + (long long)batch * NB * DD + dpart * 16;
            #pragma unroll 8
            for (int k = 0; k < KNN; ++k) {
                i32x4 v = *(const i32x4*)(qbase + (long long)idx[k] * DD);
                acc4_fp8((unsigned int)v[0], sm + 0);
                acc4_fp8((unsigned int)v[1], sm + 4);
                acc4_fp8((unsigned int)v[2], sm + 8);
                acc4_fp8((unsigned int)v[3], sm + 12);
            }

            if constexpr (V == 1) {
                float s = 0.f;
                #pragma unroll
                for (int e = 0; e < 16; ++e) s += sm[e];
                out[(long long)blockIdx.x * 256 + t] = s;   // keep live; overwritten
            } else {
                unsigned short* mrow = lds + node_local * MW + dpart * 16;
                #pragma unroll
                for (int j = 0; j < 2; ++j) {
                    u16x8 pm;
                    #pragma unroll
                    for (int e = 0; e < 8; ++e) pm[e] = f2bf(sm[j*8+e] * 0.0625f);
                    *(u16x8*)(mrow + j*8) = pm;
                }
            }
        }
    }
    if constexpr (V == 1) return;               // uniform exit, before any barrier
    __syncthreads();

    if constexpr (V == 3) {
        // stream-only: store x back out (two LDS reads to mimic full epilogue)
        const long long gbase = (long long)m_base * DD;
        const int rows_valid  = mend - m_base;
        #pragma unroll
        for (int i = 0; i < 4; ++i) {
            int flat = i * 1024 + t * 4;
            int row  = flat >> 7;
            if (row < rows_valid) {
                u16x4 uv = *(const u16x4*)(ldsx + row * MW + (flat & 127));
                u16x4 rv = *(const u16x4*)(ldsx + row * MW + (flat & 127));
                f32x4 ov;
                ov[0] = bf2f(rv[0]) + bf2f(uv[0]);
                ov[1] = bf2f(rv[1]) + bf2f(uv[1]);
                ov[2] = bf2f(rv[2]) + bf2f(uv[2]);
                ov[3] = bf2f(rv[3]) + bf2f(uv[3]);
                *(f32x4*)(out + gbase + flat) = ov;
            }
        }
        return;
    }

    // -------- Phase 2: GEMM1  h_pre = x@W1a + m@W1b
    const int wave = t >> 6;
    const int lane = t & 63;
    const int lrow = lane & 15;
    const int lk   = lane >> 4;
    const int wr   = wave & 1;
    const int wc   = wave >> 1;
    const int Arow = wr * 16 + lrow;

    bf16x8 xf[4], mf[4];
    {
        const unsigned short* xr = ldsx + Arow * MW + lk * 8;
        const unsigned short* mr = lds  + Arow * MW + lk * 8;
        #pragma unroll
        for (int ks = 0; ks < 4; ++ks) {
            xf[ks] = *(const bf16x8*)(xr + ks * 32);
            mf[ks] = *(const bf16x8*)(mr + ks * 32);
        }
    }

    f32x4 acc[4];
    #pragma unroll
    for (int f = 0; f < 4; ++f) acc[f] = (f32x4){0.f, 0.f, 0.f, 0.f};

    #pragma unroll
    for (int ks = 0; ks < 4; ++ks) {
        #pragma unroll
        for (int f = 0; f < 4; ++f) {
            int col = wc * 64 + f * 16 + lrow;
            bf16x8 bw = *(const bf16x8*)(W1aT + col * DD + ks * 32 + lk * 8);
            acc[f] = __builtin_amdgcn_mfma_f32_16x16x32_bf16(xf[ks], bw, acc[f], 0, 0, 0);
        }
    }
    #pragma unroll
    for (int ks = 0; ks < 4; ++ks) {
        #pragma unroll
        for (int f = 0; f < 4; ++f) {
            int col = wc * 64 + f * 16 + lrow;
            bf16x8 bw = *(const bf16x8*)(W1bT + col * DD + ks * 32 + lk * 8);
            acc[f] = __builtin_amdgcn_mfma_f32_16x16x32_bf16(mf[ks], bw, acc[f], 0, 0, 0);
        }
    }
    __syncthreads();

    // epilogue 1: bias + exact GELU -> h
    #pragma unroll
    for (int f = 0; f < 4; ++f) {
        int col = wc * 64 + f * 16 + lrow;
        float bb = b1[col];
        #pragma unroll
        for (int r = 0; r < 4; ++r) {
            int row = wr * 16 + lk * 4 + r;
            float xg = acc[f][r] + bb;
            float hv = 0.5f * xg * (1.0f + erff(xg * 0.70710678118654752f));
            lds[row * MW + col] = f2bf(hv);
        }
    }
    __syncthreads();

    // -------- Phase 3: GEMM2
    f32x4 acc2[4];
    #pragma unroll
    for (int f = 0; f < 4; ++f) acc2[f] = (f32x4){0.f, 0.f, 0.f, 0.f};
    {
        const unsigned short* abase = lds + Arow * MW + lk * 8;
        #pragma unroll
        for (int ks = 0; ks < 4; ++ks) {
            bf16x8 af = *(const bf16x8*)(abase + ks * 32);
            #pragma unroll
            for (int f = 0; f < 4; ++f) {
                int col = wc * 64 + f * 16 + lrow;
                bf16x8 bw = *(const bf16x8*)(W2T + col * DD + ks * 32 + lk * 8);
                acc2[f] = __builtin_amdgcn_mfma_f32_16x16x32_bf16(af, bw, acc2[f], 0, 0, 0);
            }
        }
    }
    __syncthreads();

    // epilogue 2a: bias -> upd (bf16)
    #pragma unroll
    for (int f = 0; f < 4; ++f) {
        int col = wc * 64 + f * 16 + lrow;
        float bb = b2[col];
        #pragma unroll
        for (int r = 0; r < 4; ++r) {
            int row = wr * 16 + lk * 4 + r;
            lds[row * MW + col] = f2bf(acc2[f][r] + bb);
        }
    }
    __syncthreads();

    // epilogue 2b: residual + store, 1024 B contiguous per wave store
    {
        const long long gbase = (long long)m_base * DD;
        const int rows_valid  = mend - m_base;
        #pragma unroll
        for (int i = 0; i < 4; ++i) {
            int flat = i * 1024 + t * 4;
            int row  = flat >> 7;
            if (row < rows_valid) {
                u16x4 uv = *(const u16x4*)(lds  + row * MW + (flat & 127));
                u16x4 rv = *(const u16x4*)(ldsx + row * MW + (flat & 127));
                f32x4 ov;
                ov[0] = bf2f(rv[0]) + bf2f(uv[0]);
                ov[1] = bf2f(rv[1]) + bf2f(uv[1]);
                ov[2] = bf2f(rv[2]) + bf2f(uv[2]);
                ov[3] = bf2f(rv[3]) + bf2f(uv[3]);
                *(f32x4*)(out + gbase + flat) = ov;
            }
        }
    }
}

// f32 fallback (ws too small for fp8 table) — R11 MODE 2 equivalent
__global__ __launch_bounds__(256, 4) void nr_fallback(
    const float* __restrict__ emb, const int* __restrict__ knn,
    const unsigned short* __restrict__ W1aT, const unsigned short* __restrict__ W1bT,
    const unsigned short* __restrict__ W2T,
    const float* __restrict__ b1, const float* __restrict__ b2,
    float* __restrict__ out)
{
    extern __shared__ unsigned short lds[];
    unsigned short* ldsx = lds + BM * MW;

    const int t     = threadIdx.x;
    const int xcd   = blockIdx.x & 7;
    const int slot  = blockIdx.x >> 3;
    const int batch = xcd >> 1;
    const int bib   = (xcd & 1) * NSLOT + slot;
    const int m_base = batch * NB + bib * BM;
    const int mend   = batch * NB + NB;

    {
        const int node_local = t >> 3;
        const int dpart      = t & 7;
        int m = m_base + node_local;
        if (m >= mend) m = mend - 1;

        int idx[KNN];
        const i32x4* kp4 = (const i32x4*)(knn + (long long)m * KNN);
        #pragma unroll
        for (int q = 0; q < 4; ++q) {
            i32x4 v = __builtin_nontemporal_load(kp4 + q);
            idx[4*q+0]=v[0]; idx[4*q+1]=v[1]; idx[4*q+2]=v[2]; idx[4*q+3]=v[3];
        }
        {
            const f32x4* xp = (const f32x4*)(emb + (long long)m * DD + dpart * 16);
            unsigned short* xrow = ldsx + node_local * MW + dpart * 16;
            #pragma unroll
            for (int j = 0; j < 4; ++j) {
                f32x4 v = __builtin_nontemporal_load(xp + j);
                u16x4 o;
                o[0]=f2bf(v[0]); o[1]=f2bf(v[1]); o[2]=f2bf(v[2]); o[3]=f2bf(v[3]);
                *(u16x4*)(xrow + j*4) = o;
            }
        }
        float sm[16];
        #pragma unroll
        for (int e = 0; e < 16; ++e) sm[e] = 0.f;
        const long long bbase = (long long)batch * NB * DD + dpart * 16;
        #pragma unroll 4
        for (int k = 0; k < KNN; ++k) {
            const f32x4* np = (const f32x4*)(emb + bbase + (long long)idx[k] * DD);
            #pragma unroll
            for (int j = 0; j < 4; ++j) {
                f32x4 v = np[j];
                sm[j*4+0]+=v[0]; sm[j*4+1]+=v[1]; sm[j*4+2]+=v[2]; sm[j*4+3]+=v[3];
            }
        }
        unsigned short* mrow = lds + node_local * MW + dpart * 16;
        #pragma unroll
        for (int j = 0; j < 2; ++j) {
            u16x8 pm;
            #pragma unroll
            for (int e = 0; e < 8; ++e) pm[e] = f2bf(sm[j*8+e] * 0.0625f);
            *(u16x8*)(mrow + j*8) = pm;
        }
    }
    __syncthreads();

    const int wave = t >> 6, lane = t & 63;
    const int lrow = lane & 15, lk = lane >> 4;
    const int wr = wave & 1, wc = wave >> 1;
    const int Arow = wr * 16 + lrow;

    bf16x8 xf[4], mf[4];
    {
        const unsigned short* xr = ldsx + Arow * MW + lk * 8;
        const unsigned short* mr = lds  + Arow * MW + lk * 8;
        #pragma unroll
        for (int ks = 0; ks < 4; ++ks) {
            xf[ks] = *(const bf16x8*)(xr + ks * 32);
            mf[ks] = *(const bf16x8*)(mr + ks * 32);
        }
    }
    f32x4 acc[4];
    #pragma unroll
    for (int f = 0; f < 4; ++f) acc[f] = (f32x4){0.f,0.f,0.f,0.f};
    #pragma unroll
    for (int ks = 0; ks < 4; ++ks)
        #pragma unroll
        for (int f = 0; f < 4; ++f) {
            int col = wc * 64 + f * 16 + lrow;
            bf16x8 bw = *(const bf16x8*)(W1aT + col * DD + ks * 32 + lk * 8);
            acc[f] = __builtin_amdgcn_mfma_f32_16x16x32_bf16(xf[ks], bw, acc[f], 0, 0, 0);
        }
    #pragma unroll
    for (int ks = 0; ks < 4; ++ks)
        #pragma unroll
        for (int f = 0; f < 4; ++f) {
            int col = wc * 64 + f * 16 + lrow;
            bf16x8 bw = *(const bf16x8*)(W1bT + col * DD + ks * 32 + lk * 8);
            acc[f] = __builtin_amdgcn_mfma_f32_16x16x32_bf16(mf[ks], bw, acc[f], 0, 0, 0);
        }
    __syncthreads();
    #pragma unroll
    for (int f = 0; f < 4; ++f) {
        int col = wc * 64 + f * 16 + lrow;
        float bb = b1[col];
        #pragma unroll
        for (int r = 0; r < 4; ++r) {
            int row = wr * 16 + lk * 4 + r;
            float xg = acc[f][r] + bb;
            lds[row * MW + col] = f2bf(0.5f * xg * (1.0f + erff(xg * 0.70710678118654752f)));
        }
    }
    __syncthreads();
    f32x4 acc2[4];
    #pragma unroll
    for (int f = 0; f < 4; ++f) acc2[f] = (f32x4){0.f,0.f,0.f,0.f};
    {
        const unsigned short* abase = lds + Arow * MW + lk * 8;
        #pragma unroll
        for (int ks = 0; ks < 4; ++ks) {
            bf16x8 af = *(const bf16x8*)(abase + ks * 32);
            #pragma unroll
            for (int f = 0; f < 4; ++f) {
                int col = wc * 64 + f * 16 + lrow;
                bf16x8 bw = *(const bf16x8*)(W2T + col * DD + ks * 32 + lk * 8);
                acc2[f] = __builtin_amdgcn_mfma_f32_16x16x32_bf16(af, bw, acc2[f], 0, 0, 0);
            }
        }
    }
    __syncthreads();
    #pragma unroll
    for (int f = 0; f < 4; ++f) {
        int col = wc * 64 + f * 16 + lrow;
        float bb = b2[col];
        #pragma unroll
        for (int r = 0; r < 4; ++r) {
            int row = wr * 16 + lk * 4 + r;
            lds[row * MW + col] = f2bf(acc2[f][r] + bb);
        }
    }
    __syncthreads();
    {
        const long long gbase = (long long)m_base * DD;
        const int rows_valid  = mend - m_base;
        #pragma unroll
        for (int i = 0; i < 4; ++i) {
            int flat = i * 1024 + t * 4;
            int row  = flat >> 7;
            if (row < rows_valid) {
                u16x4 uv = *(const u16x4*)(lds  + row * MW + (flat & 127));
                u16x4 rv = *(const u16x4*)(ldsx + row * MW + (flat & 127));
                f32x4 ov;
                ov[0]=bf2f(rv[0])+bf2f(uv[0]); ov[1]=bf2f(rv[1])+bf2f(uv[1]);
                ov[2]=bf2f(rv[2])+bf2f(uv[2]); ov[3]=bf2f(rv[3])+bf2f(uv[3]);
                *(f32x4*)(out + gbase + flat) = ov;
            }
        }
    }
}

extern "C" void kernel_launch(void* const* d_in, const int* in_sizes, int n_in,
                              void* d_out, int out_size, void* d_ws, size_t ws_size,
                              hipStream_t stream) {
    const float* emb = (const float*)d_in[0];
    const int*   knn = (const int*)  d_in[1];
    const float* W1  = (const float*)d_in[2];
    const float* b1  = (const float*)d_in[3];
    const float* W2  = (const float*)d_in[4];
    const float* b2  = (const float*)d_in[5];
    float* out = (float*)d_out;

    unsigned short* W1aT = (unsigned short*)d_ws;
    unsigned short* W1bT = W1aT + 16384;
    unsigned short* W2T  = W1bT + 16384;
    unsigned char*  embq = (unsigned char*)(W2T + 16384);

    const size_t NEED_FP8 = (size_t)49152 * 2 + 10240000;
    const size_t LDSB = 2 * BM * MW * 2;

    nr_prep_w<<<192, 256, 0, stream>>>(W1, W2, W1aT, W1bT, W2T);

    if (ws_size >= NEED_FP8) {
        nr_prep_q<<<5000, 256, 0, stream>>>(emb, embq);
        // diagnostic dispatches (outputs overwritten by the final full kernel)
        nr_abl<1><<<GRID_MAIN, 256, LDSB, stream>>>(emb, embq, knn, W1aT, W1bT, W2T, b1, b2, out);
        nr_abl<2><<<GRID_MAIN, 256, LDSB, stream>>>(emb, embq, knn, W1aT, W1bT, W2T, b1, b2, out);
        nr_abl<3><<<GRID_MAIN, 256, LDSB, stream>>>(emb, embq, knn, W1aT, W1bT, W2T, b1, b2, out);
        // the real kernel — writes the final correct output
        nr_abl<0><<<GRID_MAIN, 256, LDSB, stream>>>(emb, embq, knn, W1aT, W1bT, W2T, b1, b2, out);
    } else {
        nr_fallback<<<GRID_MAIN, 256, LDSB, stream>>>(emb, knn, W1aT, W1bT, W2T, b1, b2, out);
    }
}

// Round 15
// 124.605 us; speedup vs baseline: 1.6697x; 1.6697x over previous
//
#include <hip/hip_runtime.h>

// Problem constants
#define NB      20000      // nodes per batch
#define BATCH   4
#define KNN     16
#define DD      128        // embedding dim
#define BM      32         // nodes per block (32 -> 2504 blocks, ~9.8/CU)
#define MW      136        // bf16 LDS row stride, padded from 128
#define NSLOT   313        // blocks per XCD half-batch: 313*32 = 10016 rows
#define GRID_MAIN (8*NSLOT)

#if defined(__has_builtin)
#if __has_builtin(__builtin_amdgcn_cvt_pk_f32_fp8)
#define FP8_DEC_BUILTIN 1
#endif
#endif

typedef __attribute__((ext_vector_type(8))) short          bf16x8;
typedef __attribute__((ext_vector_type(4))) float          f32x4;
typedef __attribute__((ext_vector_type(2))) float          f32x2;
typedef __attribute__((ext_vector_type(4))) int            i32x4;
typedef __attribute__((ext_vector_type(2))) int            i32x2;
typedef __attribute__((ext_vector_type(4))) unsigned short u16x4;
typedef __attribute__((ext_vector_type(8))) unsigned short u16x8;

__device__ __forceinline__ unsigned short f2bf(float f) {
    unsigned int u = __float_as_uint(f);
    u += 0x7fffu + ((u >> 16) & 1u);           // round-to-nearest-even
    return (unsigned short)(u >> 16);
}
__device__ __forceinline__ float bf2f(unsigned short u) {
    return __uint_as_float((unsigned int)u << 16);
}

// tanh-form GELU: z*sigmoid(2*(c1*z + c1*0.044715*z^3)).
// max |diff| vs exact erf-GELU ~1e-4 (negligible vs 0.112 threshold).
__device__ __forceinline__ float gelu_fast(float z) {
    float u = z * (0.7978845608028654f + 0.0356774081f * z * z);
    float e = __expf(-2.0f * u);
    return z * __builtin_amdgcn_rcpf(1.0f + e);
}

__device__ __forceinline__ unsigned int f32_to_e4m3(float x) {
    unsigned int u   = __float_as_uint(x);
    unsigned int sgn = (u >> 24) & 0x80u;
    float ax = fabsf(x);
    unsigned int em;
    if (ax < 0.015625f) {                       // denormal: m * 2^-9
        em = (unsigned int)rintf(ax * 512.0f);
    } else {
        unsigned int mag = __float_as_uint(fminf(ax, 448.0f));
        em = ((mag + 0x7FFFFu + ((mag >> 20) & 1u)) >> 20) - 0x3C0u;
    }
    return sgn | em;
}

__device__ __forceinline__ void acc4_fp8(unsigned int w, float* s) {
#if defined(FP8_DEC_BUILTIN)
    f32x2 lo = __builtin_amdgcn_cvt_pk_f32_fp8((int)w, false);
    f32x2 hi = __builtin_amdgcn_cvt_pk_f32_fp8((int)w, true);
    s[0] += lo[0]; s[1] += lo[1]; s[2] += hi[0]; s[3] += hi[1];
#else
    #pragma unroll
    for (int j = 0; j < 4; ++j) {
        unsigned int b  = (w >> (8 * j)) & 0xFFu;
        unsigned int em = b & 0x7Fu;
        float f  = __uint_as_float((em << 20) + 0x3C000000u);
        float fd = (float)em * 0.001953125f;
        f = (em < 8u) ? fd : f;
        f = __uint_as_float(__float_as_uint(f) | ((b & 0x80u) << 24));
        s[j] += f;
    }
#endif
}

__global__ __launch_bounds__(256) void nr_prep_w(
    const float* __restrict__ W1, const float* __restrict__ W2,
    unsigned short* __restrict__ W1aT, unsigned short* __restrict__ W1bT,
    unsigned short* __restrict__ W2T)
{
    int tid = blockIdx.x * 256 + threadIdx.x;   // < 49152
    int col = (tid & 16383) / DD;
    int k   = (tid & 16383) % DD;
    if (tid < 16384) {
        W1aT[tid] = f2bf(W1[k * DD + col] + W1[(256 + k) * DD + col]);
    } else if (tid < 32768) {
        W1bT[tid - 16384] = f2bf(W1[(128 + k) * DD + col] - W1[(256 + k) * DD + col]);
    } else {
        W2T[tid - 32768] = f2bf(W2[k * DD + col]);
    }
}

__global__ __launch_bounds__(256) void nr_prep_q(
    const float* __restrict__ src, unsigned char* __restrict__ dstq)
{
    long long i = ((long long)blockIdx.x * 256 + threadIdx.x) * 8;
    const float4* p = (const float4*)(src + i);
    float4 a = p[0], b = p[1];
    unsigned int w0 = f32_to_e4m3(a.x) | (f32_to_e4m3(a.y) << 8) |
                      (f32_to_e4m3(a.z) << 16) | (f32_to_e4m3(a.w) << 24);
    unsigned int w1 = f32_to_e4m3(b.x) | (f32_to_e4m3(b.y) << 8) |
                      (f32_to_e4m3(b.z) << 16) | (f32_to_e4m3(b.w) << 24);
    i32x2 q; q[0] = (int)w0; q[1] = (int)w1;
    *(i32x2*)(dstq + i) = q;
}

// MODE 0: fp8 gather table (embq, 2.56 MB/batch -> L2-resident via XCD-batch
//         affinity); x staged once from f32 emb (nt) into LDS.
// MODE 2: f32 gather fallback (no table), same structure.
template<int MODE>
__global__ __launch_bounds__(256, 4) void nr_main(
    const float* __restrict__ emb, const unsigned char* __restrict__ embq,
    const int* __restrict__ knn,
    const unsigned short* __restrict__ W1aT, const unsigned short* __restrict__ W1bT,
    const unsigned short* __restrict__ W2T,
    const float* __restrict__ b1, const float* __restrict__ b2,
    float* __restrict__ out)
{
    extern __shared__ unsigned short lds[];     // [32][MW] bf16: mean -> h -> upd
    unsigned short* ldsx = lds + BM * MW;       // [32][MW] bf16: x

    const int t     = threadIdx.x;
    const int xcd   = blockIdx.x & 7;
    const int slot  = blockIdx.x >> 3;
    const int batch = xcd >> 1;
    const int bib   = (xcd & 1) * NSLOT + slot;
    const int m_base = batch * NB + bib * BM;
    const int mend   = batch * NB + NB;

    // -------- Phase 1: stage x, gather 16 neighbors (2x 8-deep), mean -> LDS
    {
        const int node_local = t >> 3;          // 0..31
        const int dpart      = t & 7;           // 16 dims each
        int m = m_base + node_local;
        if (m >= mend) m = mend - 1;

        int idx[KNN];
        const i32x4* kp4 = (const i32x4*)(knn + (long long)m * KNN);
        #pragma unroll
        for (int q = 0; q < 4; ++q) {
            i32x4 v = __builtin_nontemporal_load(kp4 + q);
            idx[4*q+0] = v[0]; idx[4*q+1] = v[1]; idx[4*q+2] = v[2]; idx[4*q+3] = v[3];
        }

        // stage x: coalesced f32 -> bf16 -> ldsx (read exactly once)
        {
            const f32x4* xp = (const f32x4*)(emb + (long long)m * DD + dpart * 16);
            unsigned short* xrow = ldsx + node_local * MW + dpart * 16;
            #pragma unroll
            for (int j = 0; j < 4; ++j) {
                f32x4 v = __builtin_nontemporal_load(xp + j);
                u16x4 o;
                o[0]=f2bf(v[0]); o[1]=f2bf(v[1]); o[2]=f2bf(v[2]); o[3]=f2bf(v[3]);
                *(u16x4*)(xrow + j*4) = o;
            }
        }

        float sm[16];
        #pragma unroll
        for (int e = 0; e < 16; ++e) sm[e] = 0.f;

        if constexpr (MODE == 0) {
            const unsigned char* qbase =
                embq + (long long)batch * NB * DD + dpart * 16;
            // batch 1: 8 loads in flight, then decode
            i32x4 g[8];
            #pragma unroll
            for (int k = 0; k < 8; ++k)
                g[k] = *(const i32x4*)(qbase + (long long)idx[k] * DD);
            #pragma unroll
            for (int k = 0; k < 8; ++k) {
                acc4_fp8((unsigned int)g[k][0], sm + 0);
                acc4_fp8((unsigned int)g[k][1], sm + 4);
                acc4_fp8((unsigned int)g[k][2], sm + 8);
                acc4_fp8((unsigned int)g[k][3], sm + 12);
            }
            // pin: batch-2 loads must NOT hoist above batch-1 decode
            // (R12/R13: hoisting re-created a 16-wide live range -> scratch spill)
            __builtin_amdgcn_sched_barrier(0);
            // batch 2
            #pragma unroll
            for (int k = 0; k < 8; ++k)
                g[k] = *(const i32x4*)(qbase + (long long)idx[8+k] * DD);
            #pragma unroll
            for (int k = 0; k < 8; ++k) {
                acc4_fp8((unsigned int)g[k][0], sm + 0);
                acc4_fp8((unsigned int)g[k][1], sm + 4);
                acc4_fp8((unsigned int)g[k][2], sm + 8);
                acc4_fp8((unsigned int)g[k][3], sm + 12);
            }
        } else {
            const long long bbase = (long long)batch * NB * DD + dpart * 16;
            #pragma unroll 4
            for (int k = 0; k < KNN; ++k) {
                const f32x4* np = (const f32x4*)(emb + bbase + (long long)idx[k] * DD);
                #pragma unroll
                for (int j = 0; j < 4; ++j) {
                    f32x4 v = np[j];
                    sm[j*4+0]+=v[0]; sm[j*4+1]+=v[1]; sm[j*4+2]+=v[2]; sm[j*4+3]+=v[3];
                }
            }
        }

        unsigned short* mrow = lds + node_local * MW + dpart * 16;
        #pragma unroll
        for (int j = 0; j < 2; ++j) {
            u16x8 pm;
            #pragma unroll
            for (int e = 0; e < 8; ++e) pm[e] = f2bf(sm[j*8+e] * 0.0625f);
            *(u16x8*)(mrow + j*8) = pm;
        }
    }
    __syncthreads();

    // -------- Phase 2: GEMM1  h_pre = x@W1a + m@W1b  (K=128 each)
    const int wave = t >> 6;
    const int lane = t & 63;
    const int lrow = lane & 15;
    const int lk   = lane >> 4;
    const int wr   = wave & 1;
    const int wc   = wave >> 1;
    const int Arow = wr * 16 + lrow;

    bf16x8 xf[4], mf[4];
    {
        const unsigned short* xr = ldsx + Arow * MW + lk * 8;
        const unsigned short* mr = lds  + Arow * MW + lk * 8;
        #pragma unroll
        for (int ks = 0; ks < 4; ++ks) {
            xf[ks] = *(const bf16x8*)(xr + ks * 32);
            mf[ks] = *(const bf16x8*)(mr + ks * 32);
        }
    }

    f32x4 acc[4];
    #pragma unroll
    for (int f = 0; f < 4; ++f) acc[f] = (f32x4){0.f, 0.f, 0.f, 0.f};

    #pragma unroll
    for (int ks = 0; ks < 4; ++ks) {
        #pragma unroll
        for (int f = 0; f < 4; ++f) {
            int col = wc * 64 + f * 16 + lrow;
            bf16x8 bw = *(const bf16x8*)(W1aT + col * DD + ks * 32 + lk * 8);
            acc[f] = __builtin_amdgcn_mfma_f32_16x16x32_bf16(xf[ks], bw, acc[f], 0, 0, 0);
        }
    }
    #pragma unroll
    for (int ks = 0; ks < 4; ++ks) {
        #pragma unroll
        for (int f = 0; f < 4; ++f) {
            int col = wc * 64 + f * 16 + lrow;
            bf16x8 bw = *(const bf16x8*)(W1bT + col * DD + ks * 32 + lk * 8);
            acc[f] = __builtin_amdgcn_mfma_f32_16x16x32_bf16(mf[ks], bw, acc[f], 0, 0, 0);
        }
    }
    __syncthreads();

    // epilogue 1: bias + fast GELU -> h (bf16) into SAME LDS region
    #pragma unroll
    for (int f = 0; f < 4; ++f) {
        int col = wc * 64 + f * 16 + lrow;
        float bb = b1[col];
        #pragma unroll
        for (int r = 0; r < 4; ++r) {
            int row = wr * 16 + lk * 4 + r;
            lds[row * MW + col] = f2bf(gelu_fast(acc[f][r] + bb));
        }
    }
    __syncthreads();

    // -------- Phase 3: GEMM2  upd = h @ W2
    f32x4 acc2[4];
    #pragma unroll
    for (int f = 0; f < 4; ++f) acc2[f] = (f32x4){0.f, 0.f, 0.f, 0.f};
    {
        const unsigned short* abase = lds + Arow * MW + lk * 8;
        #pragma unroll
        for (int ks = 0; ks < 4; ++ks) {
            bf16x8 af = *(const bf16x8*)(abase + ks * 32);
            #pragma unroll
            for (int f = 0; f < 4; ++f) {
                int col = wc * 64 + f * 16 + lrow;
                bf16x8 bw = *(const bf16x8*)(W2T + col * DD + ks * 32 + lk * 8);
                acc2[f] = __builtin_amdgcn_mfma_f32_16x16x32_bf16(af, bw, acc2[f], 0, 0, 0);
            }
        }
    }
    __syncthreads();

    // epilogue 2a: bias -> upd (bf16) in SAME LDS region
    #pragma unroll
    for (int f = 0; f < 4; ++f) {
        int col = wc * 64 + f * 16 + lrow;
        float bb = b2[col];
        #pragma unroll
        for (int r = 0; r < 4; ++r) {
            int row = wr * 16 + lk * 4 + r;
            lds[row * MW + col] = f2bf(acc2[f][r] + bb);
        }
    }
    __syncthreads();

    // epilogue 2b: residual + store; each wave store covers 1024 B contiguous
    {
        const long long gbase = (long long)m_base * DD;
        const int rows_valid  = mend - m_base;
        #pragma unroll
        for (int i = 0; i < 4; ++i) {
            int flat = i * 1024 + t * 4;
            int row  = flat >> 7;
            if (row < rows_valid) {
                u16x4 uv = *(const u16x4*)(lds  + row * MW + (flat & 127));
                u16x4 rv = *(const u16x4*)(ldsx + row * MW + (flat & 127));
                f32x4 ov;
                ov[0] = bf2f(rv[0]) + bf2f(uv[0]);
                ov[1] = bf2f(rv[1]) + bf2f(uv[1]);
                ov[2] = bf2f(rv[2]) + bf2f(uv[2]);
                ov[3] = bf2f(rv[3]) + bf2f(uv[3]);
                *(f32x4*)(out + gbase + flat) = ov;
            }
        }
    }
}

extern "C" void kernel_launch(void* const* d_in, const int* in_sizes, int n_in,
                              void* d_out, int out_size, void* d_ws, size_t ws_size,
                              hipStream_t stream) {
    const float* emb = (const float*)d_in[0];
    const int*   knn = (const int*)  d_in[1];
    const float* W1  = (const float*)d_in[2];
    const float* b1  = (const float*)d_in[3];
    const float* W2  = (const float*)d_in[4];
    const float* b2  = (const float*)d_in[5];
    float* out = (float*)d_out;

    unsigned short* W1aT = (unsigned short*)d_ws;
    unsigned short* W1bT = W1aT + 16384;
    unsigned short* W2T  = W1bT + 16384;
    unsigned char*  embq = (unsigned char*)(W2T + 16384);

    const size_t NEED_FP8 = (size_t)49152 * 2 + 10240000;
    const size_t LDSB = 2 * BM * MW * 2;

    nr_prep_w<<<192, 256, 0, stream>>>(W1, W2, W1aT, W1bT, W2T);

    if (ws_size >= NEED_FP8) {
        nr_prep_q<<<5000, 256, 0, stream>>>(emb, embq);
        nr_main<0><<<GRID_MAIN, 256, LDSB, stream>>>(
            emb, embq, knn, W1aT, W1bT, W2T, b1, b2, out);
    } else {
        nr_main<2><<<GRID_MAIN, 256, LDSB, stream>>>(
            emb, nullptr, knn, W1aT, W1bT, W2T, b1, b2, out);
    }
}